// Round 6
// baseline (156.402 us; speedup 1.0000x reference)
//
#include <hip/hip_runtime.h>
#include <math.h>

#define IMG_H 512
#define IMG_W 512
#define TILE  32
#define NSLOT 64
#define HT_S  52            // hT stride in halves: 104 B -> 26-bank stride, 2-way (free)

typedef _Float16 f16x4 __attribute__((ext_vector_type(4)));
typedef _Float16 f16x8 __attribute__((ext_vector_type(8)));
typedef _Float16 h2    __attribute__((ext_vector_type(2)));
typedef float    f32x4 __attribute__((ext_vector_type(4)));

union F16Frag { f16x8 v8; f16x4 v4[2]; };

__global__ __launch_bounds__(256, 8)
void ssim_main(const float* __restrict__ pred, const float* __restrict__ targ,
               float* __restrict__ partial, double* __restrict__ acc, int mode)
{
    __shared__ _Float16 hT[5][TILE][HT_S];   // [q][out_col][halo_row 0..47]

    const int tid  = threadIdx.x;
    const int lane = tid & 63;
    const int wave = tid >> 6;
    const int ln   = lane & 15;
    const int lg   = lane >> 4;

    const int tx = blockIdx.x, ty = blockIdx.y, img = blockIdx.z;
    const float* __restrict__ p = pred + (size_t)img * (IMG_H * IMG_W);
    const float* __restrict__ t = targ + (size_t)img * (IMG_H * IMG_W);
    const int gr0 = ty * TILE - 5;     // halo row 0 (global)
    const int wo  = tx * TILE - 8;     // halo col 0 (global), 16B-aligned
    // output col n uses halo cols n+3 .. n+13 (band offset -3)

    // ---- zero hT rows 42..47 (read by stage C with zero weight; LDS may hold NaN) ----
    // 5 q x 32 cols = 160 items, 3 h2 writes each (rows 42/43, 44/45, 46/47)
    if (tid < 160) {
        int q = tid / 32, col = tid & 31;
        *(h2*)&hT[q][col][42] = h2{(_Float16)0.f, (_Float16)0.f};
        *(h2*)&hT[q][col][44] = h2{(_Float16)0.f, (_Float16)0.f};
        *(h2*)&hT[q][col][46] = h2{(_Float16)0.f, (_Float16)0.f};
    }

    // ---- banded Gaussian weight fragments, computed arithmetically (no LDS) ----
    // Horizontal B-frag: B[k][n] = w[k-n-3];  Vertical A-frag: A[m][k] = w[k-m]
    // w[i] = 0.26601173 * exp(-(i-5)^2 / 4.5), i in 0..10 (normalized, sigma=1.5)
    f16x8 Bw, A2w;
    #pragma unroll
    for (int j = 0; j < 8; ++j) {
        int k  = lg * 8 + j;
        int ih = k - ln - 3;
        int iv = k - ln;
        float dh = (float)(ih - 5), dv = (float)(iv - 5);
        float vh = 0.26601173f * exp2f(-dh * dh * 0.32059889f);
        float vv = 0.26601173f * exp2f(-dv * dv * 0.32059889f);
        Bw[j]  = (_Float16)(((unsigned)ih <= 10u) ? vh : 0.0f);
        A2w[j] = (_Float16)(((unsigned)iv <= 10u) ? vv : 0.0f);
    }
    const f32x4 zacc = {0.f, 0.f, 0.f, 0.f};

    // ---- Stage B: horizontal conv via MFMA, A-fragments straight from global ----
    // 6 position tiles: rt in {0,1,2} (halo row bases 0,16,26) x ct in {0,1}
    auto do_tile = [&](int tt) {
        const int rt = tt >> 1, ct = tt & 1;
        const int rowbase = (rt == 2) ? 26 : rt * 16;
        const int gr = gr0 + rowbase + ln;        // global row (A row = ln)
        const int gc = wo + ct * 16 + lg * 8;     // global col base (8 floats, 32B-aligned)
        float4 pv0 = {0,0,0,0}, pv1 = {0,0,0,0}, tv0 = {0,0,0,0}, tv1 = {0,0,0,0};
        if (gr >= 0 && gr < IMG_H && gc >= 0 && gc <= IMG_W - 8) {
            const float* bp = p + (size_t)gr * IMG_W + gc;
            const float* bt = t + (size_t)gr * IMG_W + gc;
            pv0 = ((const float4*)bp)[0]; pv1 = ((const float4*)bp)[1];
            tv0 = ((const float4*)bt)[0]; tv1 = ((const float4*)bt)[1];
        }
        F16Frag pa, ta;
        pa.v8 = f16x8{(_Float16)pv0.x, (_Float16)pv0.y, (_Float16)pv0.z, (_Float16)pv0.w,
                      (_Float16)pv1.x, (_Float16)pv1.y, (_Float16)pv1.z, (_Float16)pv1.w};
        ta.v8 = f16x8{(_Float16)tv0.x, (_Float16)tv0.y, (_Float16)tv0.z, (_Float16)tv0.w,
                      (_Float16)tv1.x, (_Float16)tv1.y, (_Float16)tv1.z, (_Float16)tv1.w};
        f16x8 fq[5];
        fq[0] = pa.v8;
        fq[1] = ta.v8;
        fq[2] = pa.v8 * pa.v8;
        fq[3] = ta.v8 * ta.v8;
        fq[4] = pa.v8 * ta.v8;
        const int ocol = ct * 16 + ln;            // D col
        const int orow = rowbase + lg * 4;        // D row base (4 regs)
        #pragma unroll
        for (int q = 0; q < 5; ++q) {
            f32x4 d = __builtin_amdgcn_mfma_f32_16x16x32_f16(fq[q], Bw, zacc, 0, 0, 0);
            *(h2*)&hT[q][ocol][orow]     = h2{(_Float16)d[0], (_Float16)d[1]};
            *(h2*)&hT[q][ocol][orow + 2] = h2{(_Float16)d[2], (_Float16)d[3]};
        }
    };
    do_tile(wave);
    if (wave < 2) do_tile(wave + 4);
    __syncthreads();

    // ---- Stage C: vertical conv via MFMA (weights as A), then SSIM ----
    float lsum = 0.f;
    {
        const int ctv = wave & 1, rtv = wave >> 1;   // one 16x16 output tile per wave
        const int ocol  = ctv * 16 + ln;             // B col = output col
        const int rbase = rtv * 16 + lg * 8;         // hT row base for this k-group
        f32x4 accq[5];
        #pragma unroll
        for (int q = 0; q < 5; ++q) {
            F16Frag b;
            b.v4[0] = *(const f16x4*)&hT[q][ocol][rbase];
            b.v4[1] = *(const f16x4*)&hT[q][ocol][rbase + 4];
            accq[q] = __builtin_amdgcn_mfma_f32_16x16x32_f16(A2w, b.v8, zacc, 0, 0, 0);
        }
        const float C1 = 1e-4f, C2 = 9e-4f;
        #pragma unroll
        for (int rgi = 0; rgi < 4; ++rgi) {
            float mp = accq[0][rgi], mt = accq[1][rgi];
            float vp = accq[2][rgi] - mp * mp;
            float vt = accq[3][rgi] - mt * mt;
            float cv = accq[4][rgi] - mp * mt;
            float num = (2.f * mp * mt + C1) * (2.f * cv + C2);
            float den = (mp * mp + mt * mt + C1) * (vp + vt + C2);
            lsum = fmaf(num, __builtin_amdgcn_rcpf(den), lsum);
        }
    }

    // ---- wave reduce; per-wave slot write (mode 0) or atomic (mode 1) ----
    #pragma unroll
    for (int off = 32; off > 0; off >>= 1)
        lsum += __shfl_down(lsum, off, 64);
    if ((lane) == 0) {
        const int bid = (blockIdx.z * gridDim.y + blockIdx.y) * gridDim.x + blockIdx.x;
        if (mode == 0) {
            partial[bid * 4 + wave] = lsum;
        } else {
            atomicAdd(&acc[(bid * 4 + wave) & (NSLOT - 1)], (double)lsum);
        }
    }
}

__global__ void ssim_init(double* acc)
{
    if (threadIdx.x < NSLOT) acc[threadIdx.x] = 0.0;
}

__global__ __launch_bounds__(256)
void ssim_fin_slots(const float* __restrict__ partial, float* __restrict__ out,
                    int n4, double inv_n)
{
    __shared__ double red[4];
    double s = 0.0;
    const int tid = threadIdx.x;
    for (int i = tid; i < n4; i += 256) {
        float4 v = ((const float4*)partial)[i];
        s += (double)v.x + (double)v.y + (double)v.z + (double)v.w;
    }
    #pragma unroll
    for (int off = 32; off > 0; off >>= 1)
        s += __shfl_down(s, off, 64);
    if ((tid & 63) == 0) red[tid >> 6] = s;
    __syncthreads();
    if (tid == 0)
        out[0] = (float)(1.0 - (red[0] + red[1] + red[2] + red[3]) * inv_n);
}

__global__ void ssim_fin_atomic(const double* __restrict__ acc, float* __restrict__ out,
                                double inv_n)
{
    if (threadIdx.x == 0) {
        double s = 0.0;
        for (int i = 0; i < NSLOT; ++i) s += acc[i];
        out[0] = (float)(1.0 - s * inv_n);
    }
}

extern "C" void kernel_launch(void* const* d_in, const int* in_sizes, int n_in,
                              void* d_out, int out_size, void* d_ws, size_t ws_size,
                              hipStream_t stream)
{
    const float* pred = (const float*)d_in[0];
    const float* targ = (const float*)d_in[1];
    float* out = (float*)d_out;

    const long long total = (long long)in_sizes[0];       // 16*3*512*512
    const int n_img = (int)(total / (IMG_H * IMG_W));     // 48 planes
    dim3 grid(IMG_W / TILE, IMG_H / TILE, n_img);
    const int nblk = grid.x * grid.y * grid.z;
    const int nslots = nblk * 4;
    const double inv_n = 1.0 / (double)total;

    if (ws_size >= (size_t)nslots * sizeof(float)) {
        float* partial = (float*)d_ws;
        hipLaunchKernelGGL(ssim_main, grid, dim3(256), 0, stream,
                           pred, targ, partial, (double*)nullptr, 0);
        hipLaunchKernelGGL(ssim_fin_slots, dim3(1), dim3(256), 0, stream,
                           partial, out, nslots / 4, inv_n);
    } else {
        double* acc = (double*)d_ws;
        hipLaunchKernelGGL(ssim_init, dim3(1), dim3(64), 0, stream, acc);
        hipLaunchKernelGGL(ssim_main, grid, dim3(256), 0, stream,
                           pred, targ, (float*)nullptr, acc, 1);
        hipLaunchKernelGGL(ssim_fin_atomic, dim3(1), dim3(1), 0, stream,
                           acc, out, inv_n);
    }
}

// Round 7
// 145.769 us; speedup vs baseline: 1.0729x; 1.0729x over previous
//
#include <hip/hip_runtime.h>
#include <math.h>

#define IMG_H 512
#define IMG_W 512
#define TILE  32
#define NSLOT 64
#define SAB_R 48      // halo rows 0..47 (42 real + 6 masked-zero/unused)
#define SAB_S 56      // stride in halves: 112 B, 16B-aligned rows, 2-way banks
#define HT_S  56      // hT stride in halves

typedef _Float16 f16x4 __attribute__((ext_vector_type(4)));
typedef _Float16 f16x8 __attribute__((ext_vector_type(8)));
typedef float    f32x4 __attribute__((ext_vector_type(4)));

union F16Frag { f16x8 v8; f16x4 v4[2]; };

__global__ __launch_bounds__(256, 5)
void ssim_main(const float* __restrict__ pred, const float* __restrict__ targ,
               float* __restrict__ partial, double* __restrict__ acc, int mode)
{
    __shared__ _Float16 frags[2][64][8];          // [0]=Bw (horiz), [1]=A2w (vert)
    __shared__ _Float16 sAB[2][SAB_R][SAB_S];     // p, t halo tiles (f16)
    __shared__ _Float16 hT[5][TILE][HT_S];        // [q][out_col][halo_row 0..47]

    const int tid  = threadIdx.x;
    const int lane = tid & 63;
    const int wave = tid >> 6;
    const int ln   = lane & 15;
    const int lg   = lane >> 4;

    const int tx = blockIdx.x, ty = blockIdx.y, img = blockIdx.z;
    const float* __restrict__ p = pred + (size_t)img * (IMG_H * IMG_W);
    const float* __restrict__ t = targ + (size_t)img * (IMG_H * IMG_W);
    const int gr0 = ty * TILE - 5;     // halo row 0 (global)
    const int wo  = tx * TILE - 8;     // halo col 0 (global), 16B-aligned
    // output col n uses halo cols n+3 .. n+13 (band offset -3)

    // ---- (a) weight-fragment table: threads 0..127, one lane-fragment each ----
    // w[i] = 0.26601173 * 2^(-(i-5)^2 * 0.32059889), i in 0..10 (sigma=1.5, normalized)
    if (tid < 128) {
        const int which = tid >> 6, l = tid & 63;
        const int lln = l & 15, llg = l >> 4;
        f16x8 f;
        #pragma unroll
        for (int j = 0; j < 8; ++j) {
            int k   = llg * 8 + j;
            int idx = which ? (k - lln) : (k - lln - 3);   // A2w: w[k-m]; Bw: w[k-n-3]
            float d = (float)(idx - 5);
            float v = 0.26601173f * exp2f(-d * d * 0.32059889f);
            f[j] = (_Float16)(((unsigned)idx <= 10u) ? v : 0.0f);
        }
        *(f16x8*)&frags[which][l][0] = f;
    }

    // ---- (b) Stage A: stage p,t halo (2x aligned float4 -> f16x8 -> b128 LDS) ----
    // 48 rows x 6 groups of 8 cols = 288 items
    for (int i = tid; i < SAB_R * 6; i += 256) {
        const int r = i / 6, g = i - 6 * r;
        const int gr = gr0 + r;
        const bool in = (gr >= 0) && (gr < IMG_H) &&
                        !(tx == 0 && g == 0) && !(tx == 15 && g == 5);
        float4 p0 = {0,0,0,0}, p1 = {0,0,0,0}, t0 = {0,0,0,0}, t1 = {0,0,0,0};
        if (in) {
            const float* bp = p + (size_t)gr * IMG_W + (wo + 8 * g);
            const float* bt = t + (size_t)gr * IMG_W + (wo + 8 * g);
            p0 = ((const float4*)bp)[0]; p1 = ((const float4*)bp)[1];
            t0 = ((const float4*)bt)[0]; t1 = ((const float4*)bt)[1];
        }
        *(f16x8*)&sAB[0][r][8 * g] =
            f16x8{(_Float16)p0.x, (_Float16)p0.y, (_Float16)p0.z, (_Float16)p0.w,
                  (_Float16)p1.x, (_Float16)p1.y, (_Float16)p1.z, (_Float16)p1.w};
        *(f16x8*)&sAB[1][r][8 * g] =
            f16x8{(_Float16)t0.x, (_Float16)t0.y, (_Float16)t0.z, (_Float16)t0.w,
                  (_Float16)t1.x, (_Float16)t1.y, (_Float16)t1.z, (_Float16)t1.w};
    }
    __syncthreads();

    // ---- fragment reads (after barrier; written by (a)) ----
    const f16x8 Bw  = *(const f16x8*)&frags[0][lane][0];
    const f16x8 A2w = *(const f16x8*)&frags[1][lane][0];
    const f32x4 zacc = {0.f, 0.f, 0.f, 0.f};

    // ---- Stage B: horizontal conv via MFMA; pp/tt/pt formed on the fly ----
    // 6 tiles: rowbase in {0,16,32} x ct in {0,1}
    auto do_tile = [&](int tt) {
        const int rt = tt >> 1, ct = tt & 1;
        const int rowbase = rt * 16;
        const int arow = rowbase + ln;
        const int acol = ct * 16 + lg * 8;
        F16Frag pa, ta;
        pa.v8 = *(const f16x8*)&sAB[0][arow][acol];
        ta.v8 = *(const f16x8*)&sAB[1][arow][acol];
        f16x8 fq[5];
        fq[0] = pa.v8;
        fq[1] = ta.v8;
        fq[2] = pa.v8 * pa.v8;
        fq[3] = ta.v8 * ta.v8;
        fq[4] = pa.v8 * ta.v8;
        const int ocol = ct * 16 + ln;            // D col
        const int orow = rowbase + lg * 4;        // D row base (4 regs), 8B-aligned
        #pragma unroll
        for (int q = 0; q < 5; ++q) {
            f32x4 d = __builtin_amdgcn_mfma_f32_16x16x32_f16(fq[q], Bw, zacc, 0, 0, 0);
            *(f16x4*)&hT[q][ocol][orow] =
                f16x4{(_Float16)d[0], (_Float16)d[1], (_Float16)d[2], (_Float16)d[3]};
        }
    };
    do_tile(wave);
    if (wave < 2) do_tile(wave + 4);
    __syncthreads();

    // ---- Stage C: vertical conv via MFMA (weights as A), then SSIM ----
    float lsum = 0.f;
    {
        const int ctv = wave & 1, rtv = wave >> 1;   // one 16x16 output tile per wave
        const int ocol  = ctv * 16 + ln;             // B col = output col
        const int rbase = rtv * 16 + lg * 8;         // hT row base (16B-aligned)
        f32x4 accq[5];
        #pragma unroll
        for (int q = 0; q < 5; ++q) {
            f16x8 b = *(const f16x8*)&hT[q][ocol][rbase];
            accq[q] = __builtin_amdgcn_mfma_f32_16x16x32_f16(A2w, b, zacc, 0, 0, 0);
        }
        const float C1 = 1e-4f, C2 = 9e-4f;
        #pragma unroll
        for (int rgi = 0; rgi < 4; ++rgi) {
            float mp = accq[0][rgi], mt = accq[1][rgi];
            float vp = accq[2][rgi] - mp * mp;
            float vt = accq[3][rgi] - mt * mt;
            float cv = accq[4][rgi] - mp * mt;
            float num = (2.f * mp * mt + C1) * (2.f * cv + C2);
            float den = (mp * mp + mt * mt + C1) * (vp + vt + C2);
            lsum = fmaf(num, __builtin_amdgcn_rcpf(den), lsum);
        }
    }

    // ---- wave reduce; per-wave slot write (mode 0) or atomic (mode 1) ----
    #pragma unroll
    for (int off = 32; off > 0; off >>= 1)
        lsum += __shfl_down(lsum, off, 64);
    if (lane == 0) {
        const int bid = (blockIdx.z * gridDim.y + blockIdx.y) * gridDim.x + blockIdx.x;
        if (mode == 0) {
            partial[bid * 4 + wave] = lsum;
        } else {
            atomicAdd(&acc[(bid * 4 + wave) & (NSLOT - 1)], (double)lsum);
        }
    }
}

__global__ void ssim_init(double* acc)
{
    if (threadIdx.x < NSLOT) acc[threadIdx.x] = 0.0;
}

__global__ __launch_bounds__(1024)
void ssim_fin_slots(const float* __restrict__ partial, float* __restrict__ out,
                    int n4, double inv_n)
{
    __shared__ double red[16];
    double s = 0.0;
    const int tid = threadIdx.x;
    for (int i = tid; i < n4; i += 1024) {
        float4 v = ((const float4*)partial)[i];
        s += (double)v.x + (double)v.y + (double)v.z + (double)v.w;
    }
    #pragma unroll
    for (int off = 32; off > 0; off >>= 1)
        s += __shfl_down(s, off, 64);
    if ((tid & 63) == 0) red[tid >> 6] = s;
    __syncthreads();
    if (tid == 0) {
        double tot = 0.0;
        #pragma unroll
        for (int w = 0; w < 16; ++w) tot += red[w];
        out[0] = (float)(1.0 - tot * inv_n);
    }
}

__global__ void ssim_fin_atomic(const double* __restrict__ acc, float* __restrict__ out,
                                double inv_n)
{
    if (threadIdx.x == 0) {
        double s = 0.0;
        for (int i = 0; i < NSLOT; ++i) s += acc[i];
        out[0] = (float)(1.0 - s * inv_n);
    }
}

extern "C" void kernel_launch(void* const* d_in, const int* in_sizes, int n_in,
                              void* d_out, int out_size, void* d_ws, size_t ws_size,
                              hipStream_t stream)
{
    const float* pred = (const float*)d_in[0];
    const float* targ = (const float*)d_in[1];
    float* out = (float*)d_out;

    const long long total = (long long)in_sizes[0];       // 16*3*512*512
    const int n_img = (int)(total / (IMG_H * IMG_W));     // 48 planes
    dim3 grid(IMG_W / TILE, IMG_H / TILE, n_img);
    const int nblk = grid.x * grid.y * grid.z;
    const int nslots = nblk * 4;
    const double inv_n = 1.0 / (double)total;

    if (ws_size >= (size_t)nslots * sizeof(float)) {
        float* partial = (float*)d_ws;
        hipLaunchKernelGGL(ssim_main, grid, dim3(256), 0, stream,
                           pred, targ, partial, (double*)nullptr, 0);
        hipLaunchKernelGGL(ssim_fin_slots, dim3(1), dim3(1024), 0, stream,
                           partial, out, nslots / 4, inv_n);
    } else {
        double* acc = (double*)d_ws;
        hipLaunchKernelGGL(ssim_init, dim3(1), dim3(64), 0, stream, acc);
        hipLaunchKernelGGL(ssim_main, grid, dim3(256), 0, stream,
                           pred, targ, (float*)nullptr, acc, 1);
        hipLaunchKernelGGL(ssim_fin_atomic, dim3(1), dim3(1), 0, stream,
                           acc, out, inv_n);
    }
}